// Round 10
// baseline (945.650 us; speedup 1.0000x reference)
//
#include <hip/hip_runtime.h>

// RandomProjectionQuantizer: x(16,3000,80) f32, proj(320,16) f32, codebook(8192,16) f32
// out: argmin indices (16,750) int32.  STACK=4, 3000%4==0 -> no padding.
//
// Round-10 design notes (evidence-driven):
//  - Round 9: waves_per_eu(4,4) -> allocator collapse (VGPR=64, 1.3 GB spill, 400us).
//    Round 8's waves_per_eu(2,2) (VGPR=120, no spill) is the ONLY validated config.
//  - Round 8 occupancy was LDS-bound (64 KB -> 2 blocks/CU), not attr-bound:
//    VGPR 120 < 128-granule already permits 4 waves/EU. Fix: NSL=16 -> 32 KB LDS.
//  - Round-8 LDS reads were 2-way duplicated (rs not in address): cs widened to
//    tid&63 (4 rs-groups x 64 code-lanes) -> every b128 reads 64 distinct codes,
//    LDS wave-insts halve. Argmin butterfly widens to 64 lanes (same total order).
//  - prep_cb / prep_xp / key packing: bit-identical to validated rounds.

#define ROWS   12000   // 16 * 750
#define DIN    320     // 80 * 4
#define PD     16      // proj_dim
#define NCODES 8192

#define NSL    16             // code slices across blocks
#define SLC    (NCODES/NSL)   // 512 codes per slice (32 KB LDS)
#define RT     6              // rows per thread
#define RPB    24             // rows per block = 4 rs-groups * RT
#define NRG    (ROWS/RPB)     // 500 row-groups
#define GRID   (NRG*NSL)      // 8000 blocks

typedef unsigned long long u64;

// ---------------- codebook normalize + quarter-major slice relayout ----------------
// n = s*512 + cl (slice s=0..15), p = q*4 + j ->  word = s*8192 + q*2048 + cl*4 + j
// Hot-kernel read: code c quarter q = float4 at lds4[q*512 + c]; c = cs + 64i ->
// 64 lanes read 1024 contiguous bytes -> banks fully tiled, zero conflicts.
__global__ __launch_bounds__(256) void prep_cb(const float* __restrict__ cb,
                                               float* __restrict__ cbt) {
    int gt = blockIdx.x * 256 + threadIdx.x;          // 8192*16 threads
    int n = gt >> 4, p = gt & 15;
    float v = cb[gt];
    float ss = v * v;
    ss += __shfl_xor(ss, 1, 16);
    ss += __shfl_xor(ss, 2, 16);
    ss += __shfl_xor(ss, 4, 16);
    ss += __shfl_xor(ss, 8, 16);
    float nrm = fmaxf(sqrtf(ss), 1e-12f);             // identical numerics (validated x5)
    int s = n >> 9, cl = n & 511, q = p >> 2, j = p & 3;
    cbt[s * 8192 + q * 2048 + cl * 4 + j] = v / nrm;
}

// ---------------- projection + normalize: one thread per row (validated round 9) ----------------
__global__ __launch_bounds__(64) void prep_xp(const float* __restrict__ x,
                                              const float* __restrict__ proj,
                                              float* __restrict__ xp) {
    int r = blockIdx.x * 64 + threadIdx.x;
    if (r >= ROWS) return;
    const float4* xr = reinterpret_cast<const float4*>(x + (size_t)r * DIN);
    const float4* pr = reinterpret_cast<const float4*>(proj);   // row k = pr[k*4 .. k*4+3]

    float acc[PD];
#pragma unroll
    for (int p = 0; p < PD; ++p) acc[p] = 0.f;

#pragma unroll 4
    for (int k4 = 0; k4 < DIN / 4; ++k4) {
        float4 xv = xr[k4];
#pragma unroll
        for (int j = 0; j < 4; ++j) {
            float xs = (j == 0) ? xv.x : (j == 1) ? xv.y : (j == 2) ? xv.z : xv.w;
            const float4* prow = pr + (size_t)(k4 * 4 + j) * 4;
            float4 p0 = prow[0], p1 = prow[1], p2 = prow[2], p3 = prow[3];
            acc[ 0] = fmaf(xs, p0.x, acc[ 0]); acc[ 1] = fmaf(xs, p0.y, acc[ 1]);
            acc[ 2] = fmaf(xs, p0.z, acc[ 2]); acc[ 3] = fmaf(xs, p0.w, acc[ 3]);
            acc[ 4] = fmaf(xs, p1.x, acc[ 4]); acc[ 5] = fmaf(xs, p1.y, acc[ 5]);
            acc[ 6] = fmaf(xs, p1.z, acc[ 6]); acc[ 7] = fmaf(xs, p1.w, acc[ 7]);
            acc[ 8] = fmaf(xs, p2.x, acc[ 8]); acc[ 9] = fmaf(xs, p2.y, acc[ 9]);
            acc[10] = fmaf(xs, p2.z, acc[10]); acc[11] = fmaf(xs, p2.w, acc[11]);
            acc[12] = fmaf(xs, p3.x, acc[12]); acc[13] = fmaf(xs, p3.y, acc[13]);
            acc[14] = fmaf(xs, p3.z, acc[14]); acc[15] = fmaf(xs, p3.w, acc[15]);
        }
    }

    // exact butterfly-equivalent tree (validated round 9)
    float sq[PD];
#pragma unroll
    for (int p = 0; p < PD; ++p) sq[p] = acc[p] * acc[p];
    float t1[8], t2[4], t3[2];
#pragma unroll
    for (int i = 0; i < 8; ++i) t1[i] = sq[2 * i] + sq[2 * i + 1];
#pragma unroll
    for (int i = 0; i < 4; ++i) t2[i] = t1[2 * i] + t1[2 * i + 1];
#pragma unroll
    for (int i = 0; i < 2; ++i) t3[i] = t2[2 * i] + t2[2 * i + 1];
    float ss = t3[0] + t3[1];
    float nrm = fmaxf(sqrtf(ss), 1e-12f);

    float4* dst = reinterpret_cast<float4*>(xp + (size_t)r * PD);
#pragma unroll
    for (int q = 0; q < 4; ++q) {
        float4 o;
        o.x = acc[q * 4 + 0] / nrm;
        o.y = acc[q * 4 + 1] / nrm;
        o.z = acc[q * 4 + 2] / nrm;
        o.w = acc[q * 4 + 3] / nrm;
        dst[q] = o;
    }
}

// ---------------- fused scores + partial argmin (stage-once, 64 distinct code-lanes) ----------------
__global__ __launch_bounds__(256)
__attribute__((amdgpu_waves_per_eu(2, 2)))      // round-8-validated allocator config
void rpq_main(const float* __restrict__ xp,
              const float* __restrict__ cbt,
              u64* __restrict__ keys) {
    __shared__ __align__(16) float4 lds4[SLC * PD / 4];   // 2048 float4 = 32 KiB

    const int tid   = threadIdx.x;
    const int cs    = tid & 63;          // code lane 0..63 (all lanes distinct)
    const int rs    = tid >> 6;          // row group 0..3
    const int slice = blockIdx.x & (NSL - 1);
    const int rg    = blockIdx.x >> 4;
    const int row0  = rg * RPB + rs * RT;

    // stage the whole 32 KiB slice once: identity copy, conflict-free
    {
        const float4* src = reinterpret_cast<const float4*>(cbt) + (size_t)slice * (SLC * PD / 4);
#pragma unroll
        for (int it = 0; it < 8; ++it)
            lds4[it * 256 + tid] = src[it * 256 + tid];
    }

    // per-thread xp fragment: RT rows x 4 float4 quarters (static indexing)
    float4 xq[RT][4];
#pragma unroll
    for (int r = 0; r < RT; ++r) {
        const float4* s4 = reinterpret_cast<const float4*>(xp + (size_t)(row0 + r) * PD);
#pragma unroll
        for (int q = 0; q < 4; ++q) xq[r][q] = s4[q];
    }

    float bd[RT];
    int   bi[RT];
#pragma unroll
    for (int r = 0; r < RT; ++r) { bd[r] = 3.0e38f; bi[r] = 0; }

    __syncthreads();                     // slice staged (only barrier before epilogue)

    const float4* base = lds4 + cs;      // one base reg; q,i become imm offsets (<32 KiB)
    const int code_base = slice * SLC;

#pragma unroll
    for (int i = 0; i < SLC / 64; ++i) {             // 8 iters; 64 distinct codes/inst
        const float4 c0 = base[i * 64 +    0];       // quarter 0
        const float4 c1 = base[i * 64 +  512];       // quarter 1
        const float4 c2 = base[i * 64 + 1024];       // quarter 2
        const float4 c3 = base[i * 64 + 1536];       // quarter 3
        const int gcode = code_base + i * 64 + cs;
#pragma unroll
        for (int r = 0; r < RT; ++r) {
            float s = 0.f;                            // k-order chain identical to rounds 2-9
            s = fmaf(xq[r][0].x, c0.x, s); s = fmaf(xq[r][0].y, c0.y, s);
            s = fmaf(xq[r][0].z, c0.z, s); s = fmaf(xq[r][0].w, c0.w, s);
            s = fmaf(xq[r][1].x, c1.x, s); s = fmaf(xq[r][1].y, c1.y, s);
            s = fmaf(xq[r][1].z, c1.z, s); s = fmaf(xq[r][1].w, c1.w, s);
            s = fmaf(xq[r][2].x, c2.x, s); s = fmaf(xq[r][2].y, c2.y, s);
            s = fmaf(xq[r][2].z, c2.z, s); s = fmaf(xq[r][2].w, c2.w, s);
            s = fmaf(xq[r][3].x, c3.x, s); s = fmaf(xq[r][3].y, c3.y, s);
            s = fmaf(xq[r][3].z, c3.z, s); s = fmaf(xq[r][3].w, c3.w, s);
            float dd = 2.0f - 2.0f * s;               // same formula/codegen as validated rounds
            if (dd < bd[r]) { bd[r] = dd; bi[r] = gcode; }   // strict <, ascending codes
        }
    }

    // reduce across the 64 code-lanes of each row group (full-wave butterfly)
#pragma unroll
    for (int r = 0; r < RT; ++r) {
        unsigned ub = __float_as_uint(bd[r]);
        ub = (ub & 0x80000000u) ? ~ub : (ub | 0x80000000u);   // monotone total order
        u64 key = ((u64)ub << 32) | (unsigned)bi[r];
#pragma unroll
        for (int off = 32; off >= 1; off >>= 1) {
            u64 o = __shfl_xor(key, off, 64);
            key = (o < key) ? o : key;                // min dist, tie -> min index
        }
        if (cs == 0) keys[(size_t)slice * ROWS + row0 + r] = key;
    }
}

// ---------------- final reduce over NSL partials ----------------
__global__ __launch_bounds__(256) void rpq_reduce(const u64* __restrict__ keys,
                                                  int* __restrict__ out) {
    int r = blockIdx.x * 256 + threadIdx.x;
    if (r >= ROWS) return;
    u64 m = keys[r];
#pragma unroll
    for (int s = 1; s < NSL; ++s) {
        u64 o = keys[(size_t)s * ROWS + r];
        m = (o < m) ? o : m;
    }
    out[r] = (int)(m & 0xFFFFFFFFu);
}

extern "C" void kernel_launch(void* const* d_in, const int* in_sizes, int n_in,
                              void* d_out, int out_size, void* d_ws, size_t ws_size,
                              hipStream_t stream) {
    const float* x    = (const float*)d_in[0];   // 16*3000*80
    const float* proj = (const float*)d_in[1];   // 320*16
    const float* cb   = (const float*)d_in[2];   // 8192*16
    int* out = (int*)d_out;                      // 12000 int32

    float* cbt  = (float*)d_ws;                                    // 512 KiB @ 0
    float* xp   = (float*)((char*)d_ws + 524288);                  // 750 KiB
    u64*   keys = (u64*)  ((char*)d_ws + 524288 + 786432);         // 1.5 MiB (16 slices)

    prep_cb<<<(NCODES * PD) / 256, 256, 0, stream>>>(cb, cbt);
    prep_xp<<<(ROWS + 63) / 64, 64, 0, stream>>>(x, proj, xp);
    rpq_main<<<GRID, 256, 0, stream>>>(xp, cbt, keys);
    rpq_reduce<<<(ROWS + 255) / 256, 256, 0, stream>>>(keys, out);
}

// Round 11
// 142.174 us; speedup vs baseline: 6.6513x; 6.6513x over previous
//
#include <hip/hip_runtime.h>

// RandomProjectionQuantizer: x(16,3000,80) f32, proj(320,16) f32, codebook(8192,16) f32
// out: argmin indices (16,750) int32.  STACK=4, 3000%4==0 -> no padding.
//
// Round-11 design notes (evidence-driven):
//  - Round 8 rpq_main (59.4us, VGPR=120, zero spill) is the validated structure.
//    Round 9 (waves_per_eu(4,4)) and round 10 (full-unroll, 32-float4 window)
//    both blew the allocator (1.3-3.4 GB scratch). Lesson: keep the (2,2)
//    attribute AND the unroll-4 read window; never full-unroll ds_read loops.
//  - This round's ONE main-kernel variable: NSL 8->16 (64->32 KB LDS). Round 8
//    was LDS-residency-bound (2 blocks/CU, Occ 18.5%); VGPR=120 <= 128 already
//    permits 4 blocks/CU once LDS allows it. Everything else byte-identical.
//  - preps: round-9/10-validated one-thread-per-row prep_xp (x read once; was
//    246 MB / ~55us in round 8) + NSL=16 prep_cb + 16-way reduce.

#define ROWS   12000   // 16 * 750
#define DIN    320     // 80 * 4
#define PD     16      // proj_dim
#define NCODES 8192

#define NSL    16             // code slices across blocks
#define SLC    (NCODES/NSL)   // 512 codes per slice (32 KB LDS)
#define RT     6              // rows per thread
#define RPB    48             // rows per block = 8 rs-groups * RT (round-8 geometry)
#define NRG    (ROWS/RPB)     // 250 row-groups
#define GRID   (NRG*NSL)      // 4000 blocks

typedef unsigned long long u64;

// ---------------- codebook normalize + quarter-major slice relayout ----------------
// (exactly the round-9/10-validated version)
// n = s*512 + cl (slice s=0..15), p = q*4 + j ->  word = s*8192 + q*2048 + cl*4 + j
__global__ __launch_bounds__(256) void prep_cb(const float* __restrict__ cb,
                                               float* __restrict__ cbt) {
    int gt = blockIdx.x * 256 + threadIdx.x;          // 8192*16 threads
    int n = gt >> 4, p = gt & 15;
    float v = cb[gt];
    float ss = v * v;
    ss += __shfl_xor(ss, 1, 16);
    ss += __shfl_xor(ss, 2, 16);
    ss += __shfl_xor(ss, 4, 16);
    ss += __shfl_xor(ss, 8, 16);
    float nrm = fmaxf(sqrtf(ss), 1e-12f);             // identical numerics (validated x6)
    int s = n >> 9, cl = n & 511, q = p >> 2, j = p & 3;
    cbt[s * 8192 + q * 2048 + cl * 4 + j] = v / nrm;
}

// ---------------- projection + normalize: one thread per row ----------------
// (exactly the round-9/10-validated version; x read once, bit-identical chain)
__global__ __launch_bounds__(64) void prep_xp(const float* __restrict__ x,
                                              const float* __restrict__ proj,
                                              float* __restrict__ xp) {
    int r = blockIdx.x * 64 + threadIdx.x;
    if (r >= ROWS) return;
    const float4* xr = reinterpret_cast<const float4*>(x + (size_t)r * DIN);
    const float4* pr = reinterpret_cast<const float4*>(proj);   // row k = pr[k*4 .. k*4+3]

    float acc[PD];
#pragma unroll
    for (int p = 0; p < PD; ++p) acc[p] = 0.f;

#pragma unroll 4
    for (int k4 = 0; k4 < DIN / 4; ++k4) {
        float4 xv = xr[k4];
#pragma unroll
        for (int j = 0; j < 4; ++j) {
            float xs = (j == 0) ? xv.x : (j == 1) ? xv.y : (j == 2) ? xv.z : xv.w;
            const float4* prow = pr + (size_t)(k4 * 4 + j) * 4;
            float4 p0 = prow[0], p1 = prow[1], p2 = prow[2], p3 = prow[3];
            acc[ 0] = fmaf(xs, p0.x, acc[ 0]); acc[ 1] = fmaf(xs, p0.y, acc[ 1]);
            acc[ 2] = fmaf(xs, p0.z, acc[ 2]); acc[ 3] = fmaf(xs, p0.w, acc[ 3]);
            acc[ 4] = fmaf(xs, p1.x, acc[ 4]); acc[ 5] = fmaf(xs, p1.y, acc[ 5]);
            acc[ 6] = fmaf(xs, p1.z, acc[ 6]); acc[ 7] = fmaf(xs, p1.w, acc[ 7]);
            acc[ 8] = fmaf(xs, p2.x, acc[ 8]); acc[ 9] = fmaf(xs, p2.y, acc[ 9]);
            acc[10] = fmaf(xs, p2.z, acc[10]); acc[11] = fmaf(xs, p2.w, acc[11]);
            acc[12] = fmaf(xs, p3.x, acc[12]); acc[13] = fmaf(xs, p3.y, acc[13]);
            acc[14] = fmaf(xs, p3.z, acc[14]); acc[15] = fmaf(xs, p3.w, acc[15]);
        }
    }

    // exact butterfly-equivalent tree (validated rounds 9/10)
    float sq[PD];
#pragma unroll
    for (int p = 0; p < PD; ++p) sq[p] = acc[p] * acc[p];
    float t1[8], t2[4], t3[2];
#pragma unroll
    for (int i = 0; i < 8; ++i) t1[i] = sq[2 * i] + sq[2 * i + 1];
#pragma unroll
    for (int i = 0; i < 4; ++i) t2[i] = t1[2 * i] + t1[2 * i + 1];
#pragma unroll
    for (int i = 0; i < 2; ++i) t3[i] = t2[2 * i] + t2[2 * i + 1];
    float ss = t3[0] + t3[1];
    float nrm = fmaxf(sqrtf(ss), 1e-12f);

    float4* dst = reinterpret_cast<float4*>(xp + (size_t)r * PD);
#pragma unroll
    for (int q = 0; q < 4; ++q) {
        float4 o;
        o.x = acc[q * 4 + 0] / nrm;
        o.y = acc[q * 4 + 1] / nrm;
        o.z = acc[q * 4 + 2] / nrm;
        o.w = acc[q * 4 + 3] / nrm;
        dst[q] = o;
    }
}

// ---------------- fused scores + partial argmin ----------------
// Byte-identical structure to round 8 (59.4us validated) except SLC 1024->512:
// loop 32->16 iters (same unroll 4), staging 16->8 iters, quarter strides 512.
__global__ __launch_bounds__(256)
__attribute__((amdgpu_waves_per_eu(2, 2)))      // round-8-validated allocator config
void rpq_main(const float* __restrict__ xp,
              const float* __restrict__ cbt,
              u64* __restrict__ keys) {
    __shared__ __align__(16) float4 lds4[SLC * PD / 4];   // 2048 float4 = 32 KiB

    const int tid   = threadIdx.x;
    const int cs    = tid & 31;          // code lane (round-8 geometry)
    const int rs    = tid >> 5;          // row group 0..7
    const int slice = blockIdx.x & (NSL - 1);
    const int rg    = blockIdx.x >> 4;
    const int row0  = rg * RPB + rs * RT;

    // stage the whole 32 KiB slice once: identity copy, conflict-free
    {
        const float4* src = reinterpret_cast<const float4*>(cbt) + (size_t)slice * (SLC * PD / 4);
#pragma unroll
        for (int it = 0; it < 8; ++it)
            lds4[it * 256 + tid] = src[it * 256 + tid];
    }

    // per-thread xp fragment: RT rows x 4 float4 quarters (static indexing)
    float4 xq[RT][4];
#pragma unroll
    for (int r = 0; r < RT; ++r) {
        const float4* s4 = reinterpret_cast<const float4*>(xp + (size_t)(row0 + r) * PD);
#pragma unroll
        for (int q = 0; q < 4; ++q) xq[r][q] = s4[q];
    }

    float bd[RT];
    int   bi[RT];
#pragma unroll
    for (int r = 0; r < RT; ++r) { bd[r] = 3.0e38f; bi[r] = 0; }

    __syncthreads();                     // slice staged (only barrier before epilogue)

    const float4* base = lds4 + cs;      // one base reg; q,i become imm offsets (<32 KiB)
    const int code_base = slice * SLC;

#pragma unroll 4
    for (int i = 0; i < SLC / 32; ++i) {             // 16 iters, unroll-4 window (round 8)
        const float4 c0 = base[i * 32 +    0];       // quarter 0
        const float4 c1 = base[i * 32 +  512];       // quarter 1
        const float4 c2 = base[i * 32 + 1024];       // quarter 2
        const float4 c3 = base[i * 32 + 1536];       // quarter 3
        const int gcode = code_base + i * 32 + cs;
#pragma unroll
        for (int r = 0; r < RT; ++r) {
            float s = 0.f;                            // k-order chain identical to rounds 2-10
            s = fmaf(xq[r][0].x, c0.x, s); s = fmaf(xq[r][0].y, c0.y, s);
            s = fmaf(xq[r][0].z, c0.z, s); s = fmaf(xq[r][0].w, c0.w, s);
            s = fmaf(xq[r][1].x, c1.x, s); s = fmaf(xq[r][1].y, c1.y, s);
            s = fmaf(xq[r][1].z, c1.z, s); s = fmaf(xq[r][1].w, c1.w, s);
            s = fmaf(xq[r][2].x, c2.x, s); s = fmaf(xq[r][2].y, c2.y, s);
            s = fmaf(xq[r][2].z, c2.z, s); s = fmaf(xq[r][2].w, c2.w, s);
            s = fmaf(xq[r][3].x, c3.x, s); s = fmaf(xq[r][3].y, c3.y, s);
            s = fmaf(xq[r][3].z, c3.z, s); s = fmaf(xq[r][3].w, c3.w, s);
            float dd = 2.0f - 2.0f * s;               // same formula/codegen as validated rounds
            if (dd < bd[r]) { bd[r] = dd; bi[r] = gcode; }   // strict <, ascending codes
        }
    }

    // reduce across the 32 code-lanes of each row group (round-8 reduce, validated)
#pragma unroll
    for (int r = 0; r < RT; ++r) {
        unsigned ub = __float_as_uint(bd[r]);
        ub = (ub & 0x80000000u) ? ~ub : (ub | 0x80000000u);   // monotone total order
        u64 key = ((u64)ub << 32) | (unsigned)bi[r];
#pragma unroll
        for (int off = 16; off >= 1; off >>= 1) {
            u64 o = __shfl_xor(key, off, 32);
            key = (o < key) ? o : key;                // min dist, tie -> min index
        }
        if (cs == 0) keys[(size_t)slice * ROWS + row0 + r] = key;
    }
}

// ---------------- final reduce over NSL partials ----------------
__global__ __launch_bounds__(256) void rpq_reduce(const u64* __restrict__ keys,
                                                  int* __restrict__ out) {
    int r = blockIdx.x * 256 + threadIdx.x;
    if (r >= ROWS) return;
    u64 m = keys[r];
#pragma unroll
    for (int s = 1; s < NSL; ++s) {
        u64 o = keys[(size_t)s * ROWS + r];
        m = (o < m) ? o : m;
    }
    out[r] = (int)(m & 0xFFFFFFFFu);
}

extern "C" void kernel_launch(void* const* d_in, const int* in_sizes, int n_in,
                              void* d_out, int out_size, void* d_ws, size_t ws_size,
                              hipStream_t stream) {
    const float* x    = (const float*)d_in[0];   // 16*3000*80
    const float* proj = (const float*)d_in[1];   // 320*16
    const float* cb   = (const float*)d_in[2];   // 8192*16
    int* out = (int*)d_out;                      // 12000 int32

    float* cbt  = (float*)d_ws;                                    // 512 KiB @ 0
    float* xp   = (float*)((char*)d_ws + 524288);                  // 750 KiB
    u64*   keys = (u64*)  ((char*)d_ws + 524288 + 786432);         // 1.5 MiB (16 slices)

    prep_cb<<<(NCODES * PD) / 256, 256, 0, stream>>>(cb, cbt);
    prep_xp<<<(ROWS + 63) / 64, 64, 0, stream>>>(x, proj, xp);
    rpq_main<<<GRID, 256, 0, stream>>>(xp, cbt, keys);
    rpq_reduce<<<(ROWS + 255) / 256, 256, 0, stream>>>(keys, out);
}